// Round 1
// baseline (140.626 us; speedup 1.0000x reference)
//
#include <hip/hip_runtime.h>
#include <hip/hip_fp16.h>
#include <math.h>

#define N_NODES  50000
#define N_EDGES  800000
#define IN_DIM   64
#define HID_DIM  64
#define N_CLS    10
#define NBUCK    196      // ceil(N_NODES/256) coarse buckets (dst >> 8)
#define PBLK     256      // partition chunks/blocks
#define PCHUNK   (N_EDGES / PBLK)   // 3125 edges per chunk (exact)
#define FCAP     8192     // k_fine LDS edge cache capacity (32 KB)
#define PSTRIDE  8192     // fixed packed slots per bucket
#define CSTRIDE  8192     // fixed csr slots per bucket (max bucket ~5.3k incl pads)
#define ZROW     50000    // zero-row index for pad gathers
#define NPERM    (NBUCK * 256)   // 50176 permutation slots (includes invalid tail)

// unpack 8 fp16 (carried in a float4) and accumulate into two float4
__device__ __forceinline__ void h8_acc(float4 raw, float4& a, float4& b) {
    union { float4 f; __half2 h[4]; } u;
    u.f = raw;
    float2 p0 = __half22float2(u.h[0]);
    float2 p1 = __half22float2(u.h[1]);
    float2 p2 = __half22float2(u.h[2]);
    float2 p3 = __half22float2(u.h[3]);
    a.x += p0.x; a.y += p0.y; a.z += p1.x; a.w += p1.y;
    b.x += p2.x; b.y += p2.y; b.z += p3.x; b.w += p3.y;
}

// ---------------- init: bucket cursors to fixed region bases; zero ZROW pad rows ----------------
__global__ __launch_bounds__(256) void k_init(int* __restrict__ gcur,
                                              float2* __restrict__ xlh,
                                              __half* __restrict__ hlh) {
    int t = threadIdx.x;
    if (t < NBUCK) gcur[t] = t * PSTRIDE;
    if (t < 16) xlh[(size_t)ZROW * 16 + t] = make_float2(0.f, 0.f);
    if (t >= 16 && t < 26) hlh[(size_t)ZROW * N_CLS + (t - 16)] = __float2half(0.f);
}

// ---------------- pass 1: hist + global range reservation + scatter, one kernel ----------------
__global__ __launch_bounds__(256) void k_part1(const int* __restrict__ src,
                                               const int* __restrict__ dst,
                                               int* __restrict__ gcur,
                                               int* __restrict__ packed) {
    __shared__ int lh[NBUCK];
    __shared__ int cur[NBUCK];
    __shared__ int dcache[PCHUNK];          // 12.5 KB
    int t = threadIdx.x;
    for (int i = t; i < NBUCK; i += 256) lh[i] = 0;
    __syncthreads();
    int beg = blockIdx.x * PCHUNK;
    for (int i = t; i < PCHUNK; i += 256) {
        int d = dst[beg + i];
        dcache[i] = d;
        atomicAdd(&lh[d >> 8], 1);          // LDS atomic
    }
    __syncthreads();
    for (int i = t; i < NBUCK; i += 256)
        cur[i] = atomicAdd(&gcur[i], lh[i]);   // device-scope range reservation
    __syncthreads();
    for (int i = t; i < PCHUNK; i += 256) {
        int d = dcache[i];
        int sv = src[beg + i];
        int slot = atomicAdd(&cur[d >> 8], 1);  // LDS atomic
        packed[slot] = ((d & 255) << 16) | sv;  // into bucket's fixed region
    }
}

// ---------------- pass 2: per-bucket fine CSR (padded to x4) + off/nend + dinv + degree-sort perm ----------------
__global__ __launch_bounds__(1024) void k_fine(const int* __restrict__ packed,
                                               const int* __restrict__ gcur,
                                               int* __restrict__ off,
                                               int* __restrict__ nend,
                                               float* __restrict__ dinv,
                                               int* __restrict__ csr,
                                               int* __restrict__ gperm) {
    __shared__ int hist[256];
    __shared__ int scan[256];
    __shared__ int cur[256];
    __shared__ int dh[64];
    __shared__ int dsc[64];
    __shared__ int ecache[FCAP];            // 32 KB
    int t = threadIdx.x;
    int bucket = blockIdx.x;
    if (t < 256) hist[t] = 0;
    __syncthreads();
    int beg = bucket * PSTRIDE;
    int ne  = gcur[bucket] - beg;
    int end = beg + ne;
    bool cached = ne <= FCAP;
    if (cached) {
        for (int i = t; i < ne; i += 1024) {
            int p = packed[beg + i];
            ecache[i] = p;
            atomicAdd(&hist[p >> 16], 1);
        }
    } else {
        for (int i = beg + t; i < end; i += 1024)
            atomicAdd(&hist[packed[i] >> 16], 1);
    }
    __syncthreads();
    int padded = (t < 256) ? ((hist[t] + 3) & ~3) : 0;
    if (t < 256) scan[t] = padded;
    __syncthreads();
    for (int d = 1; d < 256; d <<= 1) {
        int v = 0;
        if (t < 256 && t >= d) v = scan[t - d];
        __syncthreads();
        if (t < 256 && t >= d) scan[t] += v;
        __syncthreads();
    }
    int base = bucket * CSTRIDE;
    if (t < 256) {
        int o = base + scan[t] - padded;             // exclusive padded prefix
        cur[t] = o;
        int node = bucket * 256 + t;
        if (node < N_NODES) {
            off[node]  = o;
            nend[node] = o + padded;
            dinv[node] = rsqrtf((float)(hist[t] + 1));   // +1 self-loop
        }
    }
    __syncthreads();
    if (cached) {
        for (int i = t; i < ne; i += 1024) {
            int p = ecache[i];
            int slot = atomicAdd(&cur[p >> 16], 1);      // LDS atomic
            csr[slot] = p & 0xFFFF;
        }
    } else {
        for (int i = beg + t; i < end; i += 1024) {
            int p = packed[i];
            int slot = atomicAdd(&cur[p >> 16], 1);
            csr[slot] = p & 0xFFFF;
        }
    }
    __syncthreads();
    if (t < 256) {
        int node = bucket * 256 + t;
        if (node < N_NODES) {
            int e2 = nend[node];
            for (int i = cur[t]; i < e2; ++i) csr[i] = ZROW;   // <=3 pad fills
        }
    }
    // ---- degree-DESCENDING counting sort -> gperm (equalize wave trip counts) ----
    __syncthreads();
    if (t < 64) dh[t] = 0;
    __syncthreads();
    int dbin = 0;
    if (t < 256) {
        dbin = 63 - min(hist[t], 63);        // descending: heavy nodes first (LPT)
        atomicAdd(&dh[dbin], 1);
    }
    __syncthreads();
    if (t < 64) dsc[t] = dh[t];
    __syncthreads();
    for (int d = 1; d < 64; d <<= 1) {
        int v = 0;
        if (t < 64 && t >= d) v = dsc[t - d];
        __syncthreads();
        if (t < 64 && t >= d) dsc[t] += v;
        __syncthreads();
    }
    if (t < 64) dh[t] = dsc[t] - dh[t];      // exclusive base per bin
    __syncthreads();
    if (t < 256) {
        int rank = atomicAdd(&dh[dbin], 1);
        gperm[bucket * 256 + rank] = bucket * 256 + t;  // invalid tail nodes included (guarded later)
    }
}

// ---------------- xl' = fp16((x @ W1) * dinv[row]) — 16-row tile, all-LDS inner loop ----------------
__global__ __launch_bounds__(256) void k_xw64(const float* __restrict__ x,
                                              const float* __restrict__ W,
                                              const float* __restrict__ dinv,
                                              float2* __restrict__ out /* fp16x4 */) {
    __shared__ float4 sW4[IN_DIM * 16];   // W1: 64 rows x 16 col-quads (16 KB)
    __shared__ float4 sx4[16 * 16];       // x tile: 16 rows x 16 k-quads (4 KB)
    int tid = threadIdx.x;
    const float4* W4 = (const float4*)W;
#pragma unroll
    for (int i = 0; i < 4; ++i) sW4[tid + 256 * i] = W4[tid + 256 * i];
    int rowbase = blockIdx.x * 16;
    sx4[tid] = ((const float4*)(x + (size_t)rowbase * IN_DIM))[tid];  // coalesced
    __syncthreads();
    int r  = tid >> 4;     // row in tile
    int cq = tid & 15;     // col quad
    const float4* sxr = &sx4[r * 16];
    float ax = 0.0f, ay = 0.0f, az = 0.0f, aw = 0.0f;
#pragma unroll
    for (int k4 = 0; k4 < 16; ++k4) {
        float4 xv = sxr[k4];
        float4 w0 = sW4[(k4 * 4 + 0) * 16 + cq];
        float4 w1 = sW4[(k4 * 4 + 1) * 16 + cq];
        float4 w2 = sW4[(k4 * 4 + 2) * 16 + cq];
        float4 w3 = sW4[(k4 * 4 + 3) * 16 + cq];
        ax += xv.x * w0.x + xv.y * w1.x + xv.z * w2.x + xv.w * w3.x;
        ay += xv.x * w0.y + xv.y * w1.y + xv.z * w2.y + xv.w * w3.y;
        az += xv.x * w0.z + xv.y * w1.z + xv.z * w2.z + xv.w * w3.z;
        aw += xv.x * w0.w + xv.y * w1.w + xv.z * w2.w + xv.w * w3.w;
    }
    int row = rowbase + r;
    float dv = dinv[row];
    union { __half2 h[2]; float2 f; } u;
    u.h[0] = __floats2half2_rn(ax * dv, ay * dv);
    u.h[1] = __floats2half2_rn(az * dv, aw * dv);
    out[(size_t)row * 16 + cq] = u.f;
}

// ---------------- fused layer-1 gather + relu + (h@W2)*dinv -> fp16 hl' ----------------
// 8 lanes per node (8 dims each, float4=fp16x8 gathers); degree-sorted perm -> uniform wave trips.
__global__ __launch_bounds__(256) void k_gather64(const float4* __restrict__ xlph,
                                                  const int* __restrict__ csr,
                                                  const int* __restrict__ off,
                                                  const int* __restrict__ nend,
                                                  const float* __restrict__ dinv,
                                                  const float* __restrict__ b1,
                                                  const float* __restrict__ W2,
                                                  const int* __restrict__ gperm,
                                                  __half* __restrict__ hlh /* stride 10 */) {
    __shared__ float sW2[HID_DIM][N_CLS + 1];   // pad 11 -> cheap 2-way bank alias
    int tid = threadIdx.x;
    for (int i = tid; i < HID_DIM * N_CLS; i += 256)
        sW2[i / N_CLS][i - (i / N_CLS) * N_CLS] = W2[i];
    __syncthreads();
    int gid = blockIdx.x * 32 + (tid >> 3);    // 1568 * 32 = 50176 = NPERM exact
    int d8 = tid & 7;
    int node = gperm[gid];
    bool valid = node < N_NODES;
    int nd = valid ? node : ZROW;
    int beg = 0, end = 0;
    if (valid) { beg = off[node]; end = nend[node]; }
    float4 aA = make_float4(0.f, 0.f, 0.f, 0.f);
    float4 aB = make_float4(0.f, 0.f, 0.f, 0.f);
    h8_acc(xlph[(size_t)nd * 8 + d8], aA, aB);   // self-loop (dinv[src] folded in)
    int j = beg;
    for (; j + 8 <= end; j += 8) {               // 2 int4 index loads + 8 float4 gathers
        int4 c0 = *(const int4*)(csr + j);
        int4 c1 = *(const int4*)(csr + j + 4);
        float4 r0 = xlph[(size_t)c0.x * 8 + d8];
        float4 r1 = xlph[(size_t)c0.y * 8 + d8];
        float4 r2 = xlph[(size_t)c0.z * 8 + d8];
        float4 r3 = xlph[(size_t)c0.w * 8 + d8];
        float4 r4 = xlph[(size_t)c1.x * 8 + d8];
        float4 r5 = xlph[(size_t)c1.y * 8 + d8];
        float4 r6 = xlph[(size_t)c1.z * 8 + d8];
        float4 r7 = xlph[(size_t)c1.w * 8 + d8];
        h8_acc(r0, aA, aB); h8_acc(r1, aA, aB);
        h8_acc(r2, aA, aB); h8_acc(r3, aA, aB);
        h8_acc(r4, aA, aB); h8_acc(r5, aA, aB);
        h8_acc(r6, aA, aB); h8_acc(r7, aA, aB);
    }
    if (j < end) {                               // exactly one padded 4-block
        int4 c0 = *(const int4*)(csr + j);
        float4 r0 = xlph[(size_t)c0.x * 8 + d8];
        float4 r1 = xlph[(size_t)c0.y * 8 + d8];
        float4 r2 = xlph[(size_t)c0.z * 8 + d8];
        float4 r3 = xlph[(size_t)c0.w * 8 + d8];
        h8_acc(r0, aA, aB); h8_acc(r1, aA, aB);
        h8_acc(r2, aA, aB); h8_acc(r3, aA, aB);
    }
    float dv = valid ? dinv[node] : 0.0f;
    float4 b1a = ((const float4*)b1)[d8 * 2];
    float4 b1b = ((const float4*)b1)[d8 * 2 + 1];
    float h0 = fmaxf(dv * aA.x + b1a.x, 0.0f);   // h[8*d8+0..7] in registers
    float h1 = fmaxf(dv * aA.y + b1a.y, 0.0f);
    float h2 = fmaxf(dv * aA.z + b1a.z, 0.0f);
    float h3 = fmaxf(dv * aA.w + b1a.w, 0.0f);
    float h4 = fmaxf(dv * aB.x + b1b.x, 0.0f);
    float h5 = fmaxf(dv * aB.y + b1b.y, 0.0f);
    float h6 = fmaxf(dv * aB.z + b1b.z, 0.0f);
    float h7 = fmaxf(dv * aB.w + b1b.w, 0.0f);
    float p[N_CLS];
    int k0 = d8 * 8;
#pragma unroll
    for (int c = 0; c < N_CLS; ++c)
        p[c] = h0 * sW2[k0 + 0][c] + h1 * sW2[k0 + 1][c]
             + h2 * sW2[k0 + 2][c] + h3 * sW2[k0 + 3][c]
             + h4 * sW2[k0 + 4][c] + h5 * sW2[k0 + 5][c]
             + h6 * sW2[k0 + 6][c] + h7 * sW2[k0 + 7][c];
#pragma unroll
    for (int k = 1; k < 8; k <<= 1) {
#pragma unroll
        for (int c = 0; c < N_CLS; ++c) p[c] += __shfl_xor(p[c], k, 64);
    }
    if (valid) {
        float vsel = p[0];
#pragma unroll
        for (int c = 1; c < 8; ++c) vsel = (d8 == c) ? p[c] : vsel;
        hlh[(size_t)node * N_CLS + d8] = __float2half(vsel * dv);
        if (d8 < 2)
            hlh[(size_t)node * N_CLS + 8 + d8] = __float2half(((d8 == 0) ? p[8] : p[9]) * dv);
    }
}

// ---------------- layer-2 gather (fp16 hl) + b2 + log_softmax, 16-lane group per node ----------------
__global__ __launch_bounds__(256) void k_gather10(const __half* __restrict__ hlh,
                                                  const int* __restrict__ csr,
                                                  const int* __restrict__ off,
                                                  const int* __restrict__ nend,
                                                  const float* __restrict__ dinv,
                                                  const float* __restrict__ b2,
                                                  const int* __restrict__ gperm,
                                                  float* __restrict__ out) {
    int t = threadIdx.x;
    int gid = blockIdx.x * 16 + (t >> 4);      // 3136 * 16 = 50176 = NPERM exact
    int d = t & 15;
    int node = gperm[gid];
    bool valid = node < N_NODES;
    bool act = valid && (d < N_CLS);
    int dd = (d < N_CLS) ? d : 0;
    int nd = valid ? node : ZROW;
    int beg = 0, end = 0;
    if (valid) { beg = off[node]; end = nend[node]; }
    float acc = act ? __half2float(hlh[(size_t)nd * N_CLS + dd]) : 0.0f;
    int j = beg;
    for (; j + 8 <= end; j += 8) {
        int4 c0 = *(const int4*)(csr + j);
        int4 c1 = *(const int4*)(csr + j + 4);
        float v0 = __half2float(hlh[(size_t)c0.x * N_CLS + dd]);
        float v1 = __half2float(hlh[(size_t)c0.y * N_CLS + dd]);
        float v2 = __half2float(hlh[(size_t)c0.z * N_CLS + dd]);
        float v3 = __half2float(hlh[(size_t)c0.w * N_CLS + dd]);
        float v4 = __half2float(hlh[(size_t)c1.x * N_CLS + dd]);
        float v5 = __half2float(hlh[(size_t)c1.y * N_CLS + dd]);
        float v6 = __half2float(hlh[(size_t)c1.z * N_CLS + dd]);
        float v7 = __half2float(hlh[(size_t)c1.w * N_CLS + dd]);
        if (act) acc += ((v0 + v1) + (v2 + v3)) + ((v4 + v5) + (v6 + v7));
    }
    if (j < end) {
        int4 c0 = *(const int4*)(csr + j);
        float v0 = __half2float(hlh[(size_t)c0.x * N_CLS + dd]);
        float v1 = __half2float(hlh[(size_t)c0.y * N_CLS + dd]);
        float v2 = __half2float(hlh[(size_t)c0.z * N_CLS + dd]);
        float v3 = __half2float(hlh[(size_t)c0.w * N_CLS + dd]);
        if (act) acc += (v0 + v1) + (v2 + v3);
    }
    float v = act ? dinv[node] * acc + b2[dd] : -INFINITY;
    float m = v;
#pragma unroll
    for (int k = 1; k < 16; k <<= 1) m = fmaxf(m, __shfl_xor(m, k, 64));
    float ex = act ? expf(v - m) : 0.0f;
    float ssum = ex;
#pragma unroll
    for (int k = 1; k < 16; k <<= 1) ssum += __shfl_xor(ssum, k, 64);
    if (act) out[(size_t)node * N_CLS + d] = v - m - logf(ssum);
}

extern "C" void kernel_launch(void* const* d_in, const int* in_sizes, int n_in,
                              void* d_out, int out_size, void* d_ws, size_t ws_size,
                              hipStream_t stream) {
    const float* x  = (const float*)d_in[0];
    const int*   ei = (const int*)d_in[1];
    const float* W1 = (const float*)d_in[2];
    const float* b1 = (const float*)d_in[3];
    const float* W2 = (const float*)d_in[4];
    const float* b2 = (const float*)d_in[5];
    float* out = (float*)d_out;

    const int* src = ei;             // edge_index[0]
    const int* dst = ei + N_EDGES;   // edge_index[1]

    // workspace layout (all segment starts 16B-aligned)
    int*    gcur   = (int*)d_ws;                   // 256
    int*    off    = gcur + 256;                   // 50048
    int*    nend   = off + 50048;                  // 50048
    int*    gperm  = nend + 50048;                 // 50176 (degree-sorted node order)
    int*    packed = gperm + NPERM;                // 196*8192 = 1605632 (6.4 MB)
    int*    csr    = packed + NBUCK * PSTRIDE;     // 196*8192 = 1605632 (6.4 MB)
    float*  dinv   = (float*)(csr + NBUCK * CSTRIDE); // 50048
    float2* xlh    = (float2*)(dinv + 50048);      // fp16 xl': 50001 rows x 16 float2
    __half* hlh    = (__half*)(xlh + (size_t)(N_NODES + 1) * 16);  // fp16 hl': 50001 x 10

    const int B = 256;
    int g_x64 = N_NODES / 16;                     // 3125 exact
    int g_g64 = NPERM / 32;                       // 1568 exact
    int g_g10 = NPERM / 16;                       // 3136 exact

    k_init    <<<1,     B, 0, stream>>>(gcur, xlh, hlh);
    k_part1   <<<PBLK,  B, 0, stream>>>(src, dst, gcur, packed);
    k_fine    <<<NBUCK, 1024, 0, stream>>>(packed, gcur, off, nend, dinv, csr, gperm);
    k_xw64    <<<g_x64,   B, 0, stream>>>(x, W1, dinv, xlh);
    k_gather64<<<g_g64,   B, 0, stream>>>((const float4*)xlh, csr, off, nend, dinv, b1, W2, gperm, hlh);
    k_gather10<<<g_g10,   B, 0, stream>>>(hlh, csr, off, nend, dinv, b2, gperm, out);
    (void)in_sizes; (void)n_in; (void)out_size; (void)ws_size;
}